// Round 13
// baseline (817.637 us; speedup 1.0000x reference)
//
#include <hip/hip_runtime.h>
#include <hip/hip_cooperative_groups.h>
#include <hip/hip_fp16.h>

namespace cg = cooperative_groups;

#define N_NODES   100000
#define N_EDGES   1000000
#define HID       64
#define NUM_GRAPHS 1024
#define NREP      8    // outsum atomic replicas
#define CAP       64   // max in-degree bucket capacity (Poisson(10): max deg ~30)
#define NITER     16   // fallback agg_gemm_relu: 64 nodes/block

typedef _Float16 h16;

static __device__ __forceinline__ int pack2(float a, float b) {
    union { h16 h[2]; int i; } u;
    u.h[0] = (h16)a; u.h[1] = (h16)b;
    return u.i;
}
static __device__ __forceinline__ float uni_f(float x) {
    return __int_as_float(__builtin_amdgcn_readfirstlane(__float_as_int(x)));
}

// edge gather: inputs pre-scaled by dinv[src]; per-edge = readlane + load +
// cvt + add; unmasked chunks (16 + binary tail 8/4/2/1) for MLP.
template <int U>
static __device__ __forceinline__ float agg_chunk(const h16* __restrict__ XW,
                                                  int es, int j, int lane) {
    int ss[U]; float vv[U];
    #pragma unroll
    for (int u = 0; u < U; u++) ss[u] = __builtin_amdgcn_readlane(es, j + u);
    #pragma unroll
    for (int u = 0; u < U; u++)
        vv[u] = (float)XW[(((unsigned)ss[u]) << 6) | (unsigned)lane];
    float a = 0.f;
    #pragma unroll
    for (int u = 0; u < U; u++) a += vv[u];
    return a;
}

static __device__ __forceinline__ float agg_edges(const h16* __restrict__ XW,
                                                  const int* __restrict__ ebuf,
                                                  int wid, int deg, int lane) {
    if (deg <= 0) return 0.f;
    int es = ebuf[wid * CAP + (lane < deg ? lane : deg - 1)];
    float acc = 0.f;
    int j = 0;
    for (; j + 16 <= deg; j += 16) { acc += agg_chunk<16>(XW, es, j, lane); }
    if (deg & 8) { acc += agg_chunk<8>(XW, es, j, lane); j += 8; }
    if (deg & 4) { acc += agg_chunk<4>(XW, es, j, lane); j += 4; }
    if (deg & 2) { acc += agg_chunk<2>(XW, es, j, lane); j += 2; }
    if (deg & 1) { acc += agg_chunk<1>(XW, es, j, lane); }
    return acc;
}

// =================== cooperative mega-kernel (grid-size agnostic) ===========

__global__ __launch_bounds__(256, 4) void fused(
        const int* __restrict__ src, const int* __restrict__ dst,
        const float* __restrict__ X,
        const float* __restrict__ W1, const float* __restrict__ b1,
        const float* __restrict__ W2, const float* __restrict__ b2,
        const float* __restrict__ Wout, const float* __restrict__ bout,
        const int* __restrict__ batch,
        h16* __restrict__ xw, h16* __restrict__ y2,
        int* __restrict__ ebuf, int* __restrict__ cnt,
        float* __restrict__ outsum, float* __restrict__ dinv,
        float* __restrict__ out) {
    cg::grid_group grid = cg::this_grid();
    __shared__ float Wl[4096];    // W1 flat (phase 2), W2 quad layout (phase 3)
    __shared__ float hbuf[256];   // 4 waves x 64, wave-private slices

    const int t = threadIdx.x, lane = t & 63, w = t >> 6;
    const int bid = blockIdx.x, nb = gridDim.x;

    // ---- phase 0: zero cnt + outsum (contiguous) ----
    for (int i = bid * 256 + t; i < N_NODES + NREP * NUM_GRAPHS; i += nb * 256)
        cnt[i] = 0;   // outsum immediately follows cnt
    grid.sync();

    // ---- phase 1: XCD-partitioned bucket fill ----
    {
        int part = bid & 7;
        for (int chunk = bid >> 3; chunk < (N_EDGES + 255) / 256; chunk += nb >> 3) {
            int e = chunk * 256 + t;
            if (e < N_EDGES) {
                int d = dst[e];
                if (((d >> 7) & 7) == part) {
                    int p = atomicAdd(&cnt[d], 1);
                    if (p < CAP) ebuf[(size_t)d * CAP + p] = src[e];
                }
            }
        }
    }
    grid.sync();

    // ---- phase 2: XW' = (X @ W1) * dinv + node_prep (2 threads/row) ----
    #pragma unroll
    for (int i = 0; i < 4; i++) {
        int idx = (t + i * 256) * 4;
        *(float4*)(Wl + idx) = *(const float4*)(W1 + idx);
    }
    __syncthreads();
    for (int rb = bid; rb < (N_NODES + 127) / 128; rb += nb) {
        int row = rb * 128 + (t >> 1);
        if (row < N_NODES) {
            int half = t & 1;
            float df = (float)(min(cnt[row], CAP) + 1);   // +1 self loop
            float sc = rsqrtf(df);
            if (half == 0) dinv[row] = sc;

            const float4* xr = (const float4*)(X + (size_t)row * 64);
            float4 acc[8];
            #pragma unroll
            for (int j = 0; j < 8; j++) acc[j] = make_float4(0.f, 0.f, 0.f, 0.f);
            const float* wb = Wl + half * 32;
            #pragma unroll
            for (int k4 = 0; k4 < 16; k4++) {
                float4 xv = xr[k4];
                #pragma unroll
                for (int kk = 0; kk < 4; kk++) {
                    float xk = (kk == 0) ? xv.x : (kk == 1) ? xv.y
                             : (kk == 2) ? xv.z : xv.w;
                    const float4* wr = (const float4*)(wb + (k4 * 4 + kk) * 64);
                    #pragma unroll
                    for (int j = 0; j < 8; j++) {
                        float4 wv = wr[j];
                        acc[j].x += xk * wv.x;
                        acc[j].y += xk * wv.y;
                        acc[j].z += xk * wv.z;
                        acc[j].w += xk * wv.w;
                    }
                }
            }
            int4* yr = (int4*)(xw + (size_t)row * 64 + half * 32);
            #pragma unroll
            for (int j = 0; j < 4; j++) {
                float4 a = acc[2 * j], b = acc[2 * j + 1];
                int4 o;
                o.x = pack2(a.x * sc, a.y * sc); o.y = pack2(a.z * sc, a.w * sc);
                o.z = pack2(b.x * sc, b.y * sc); o.w = pack2(b.z * sc, b.w * sc);
                yr[j] = o;
            }
        }
    }
    grid.sync();

    // ---- phase 3: agg1 + bias + ReLU + (h @ W2)*dinv -> y2 ----
    __syncthreads();   // all waves done reading Wl as W1
    #pragma unroll
    for (int i = 0; i < 16; i++) {
        int L = t + i * 256;            // L = k*64 + c
        int k = L >> 6, c = L & 63;
        Wl[(k >> 2) * 256 + c * 4 + (k & 3)] = W2[L];
    }
    __syncthreads();
    {
        float* hb = hbuf + w * 64;
        float bl = b1[lane];
        for (int grp = bid; grp < (N_NODES + 3) / 4; grp += nb) {
            int wid = __builtin_amdgcn_readfirstlane(grp * 4 + w);
            if (wid < N_NODES) {
                int deg = min(__builtin_amdgcn_readfirstlane(cnt[wid]), CAP);
                float dvw = uni_f(dinv[wid]);
                float acc = (float)xw[(((unsigned)wid) << 6) | (unsigned)lane];
                acc += agg_edges(xw, ebuf, wid, deg, lane);
                float h = fmaxf(fmaf(dvw, acc, bl), 0.f);

                hb[lane] = h;   // wave-private slice
                float y = 0.f;
                #pragma unroll
                for (int k4 = 0; k4 < 16; k4++) {
                    float4 hp = *(const float4*)(hb + k4 * 4);          // broadcast
                    float4 wq = *(const float4*)(Wl + k4 * 256 + lane * 4);
                    y = fmaf(hp.x, wq.x, y);
                    y = fmaf(hp.y, wq.y, y);
                    y = fmaf(hp.z, wq.z, y);
                    y = fmaf(hp.w, wq.w, y);
                }
                y2[(((unsigned)wid) << 6) | (unsigned)lane] = (h16)(y * dvw);
            }
        }
    }
    grid.sync();

    // ---- phase 4: agg2 + bias + ReLU + dot(Wout) + per-graph accumulate ----
    {
        float bl = b2[lane];
        float wo = Wout[lane];
        for (int grp = bid; grp < (N_NODES + 3) / 4; grp += nb) {
            int wid = __builtin_amdgcn_readfirstlane(grp * 4 + w);
            if (wid < N_NODES) {
                int deg = min(__builtin_amdgcn_readfirstlane(cnt[wid]), CAP);
                float dvw = uni_f(dinv[wid]);
                float acc = (float)y2[(((unsigned)wid) << 6) | (unsigned)lane];
                acc += agg_edges(y2, ebuf, wid, deg, lane);
                float h = fmaxf(fmaf(dvw, acc, bl), 0.f);
                float v = h * wo;
                #pragma unroll
                for (int off = 32; off > 0; off >>= 1) v += __shfl_down(v, off, 64);
                if (lane == 0) {
                    int g = batch[wid];
                    atomicAdd(&outsum[(wid & (NREP - 1)) * NUM_GRAPHS + g], v);
                }
            }
        }
    }
    grid.sync();

    // ---- phase 5: finalize (mean over batch counts via binary search) ----
    for (int g = bid * 256 + t; g < NUM_GRAPHS; g += nb * 256) {
        float s = 0.f;
        #pragma unroll
        for (int r = 0; r < NREP; r++) s += outsum[r * NUM_GRAPHS + g];
        int lo = 0, hi = N_NODES;
        while (lo < hi) { int mid = (lo + hi) >> 1; if (batch[mid] <  g) lo = mid + 1; else hi = mid; }
        int lo2 = lo, hi2 = N_NODES;
        while (lo2 < hi2) { int mid = (lo2 + hi2) >> 1; if (batch[mid] <= g) lo2 = mid + 1; else hi2 = mid; }
        float c = (float)max(lo2 - lo, 1);
        out[g] = s / c + bout[0];
    }
}

// =================== fallback path: R10 kernels (known-good, ~255us) ========

__global__ __launch_bounds__(256) void bucket_fill(const int* __restrict__ src,
                                                   const int* __restrict__ dst,
                                                   int* __restrict__ cnt,
                                                   int* __restrict__ ebuf) {
    int part  = blockIdx.x & 7;
    int e     = (blockIdx.x >> 3) * 256 + threadIdx.x;
    if (e >= N_EDGES) return;
    int d = dst[e];
    if (((d >> 7) & 7) != part) return;
    int p = atomicAdd(&cnt[d], 1);
    if (p < CAP) ebuf[(size_t)d * CAP + p] = src[e];
}

__global__ __launch_bounds__(256) void gemm64h(const float* __restrict__ X,
                                               const float* __restrict__ W,
                                               const int* __restrict__ cnt,
                                               float* __restrict__ dinv,
                                               h16* __restrict__ Y, int nrows) {
    __shared__ float Wl[4096];
    int t = threadIdx.x;
    #pragma unroll
    for (int i = 0; i < 4; i++) {
        int idx = (t + i * 256) * 4;
        *(float4*)(Wl + idx) = *(const float4*)(W + idx);
    }
    __syncthreads();
    int row  = blockIdx.x * 128 + (t >> 1);
    if (row >= nrows) return;
    int half = t & 1;
    float df = (float)(min(cnt[row], CAP) + 1);
    float sc = rsqrtf(df);
    if (half == 0) dinv[row] = sc;
    const float4* xr = (const float4*)(X + (size_t)row * 64);
    float4 acc[8];
    #pragma unroll
    for (int j = 0; j < 8; j++) acc[j] = make_float4(0.f, 0.f, 0.f, 0.f);
    const float* wb = Wl + half * 32;
    #pragma unroll
    for (int k4 = 0; k4 < 16; k4++) {
        float4 xv = xr[k4];
        #pragma unroll
        for (int kk = 0; kk < 4; kk++) {
            float xk = (kk == 0) ? xv.x : (kk == 1) ? xv.y : (kk == 2) ? xv.z : xv.w;
            const float4* wr = (const float4*)(wb + (k4 * 4 + kk) * 64);
            #pragma unroll
            for (int j = 0; j < 8; j++) {
                float4 wv = wr[j];
                acc[j].x += xk * wv.x;
                acc[j].y += xk * wv.y;
                acc[j].z += xk * wv.z;
                acc[j].w += xk * wv.w;
            }
        }
    }
    int4* yr = (int4*)(Y + (size_t)row * 64 + half * 32);
    #pragma unroll
    for (int j = 0; j < 4; j++) {
        float4 a = acc[2 * j], b = acc[2 * j + 1];
        int4 o;
        o.x = pack2(a.x * sc, a.y * sc); o.y = pack2(a.z * sc, a.w * sc);
        o.z = pack2(b.x * sc, b.y * sc); o.w = pack2(b.z * sc, b.w * sc);
        yr[j] = o;
    }
}

__global__ __launch_bounds__(256) void agg_gemm_relu(const h16* __restrict__ XW,
                                                     const int* __restrict__ cnt,
                                                     const int* __restrict__ ebuf,
                                                     const float* __restrict__ dinv,
                                                     const float* __restrict__ bias,
                                                     const float* __restrict__ W2,
                                                     h16* __restrict__ Y2) {
    __shared__ float W2q[4096];
    __shared__ float hbuf[256];
    int t = threadIdx.x;
    #pragma unroll
    for (int i = 0; i < 16; i++) {
        int L = t + i * 256;
        int k = L >> 6, c = L & 63;
        W2q[(k >> 2) * 256 + c * 4 + (k & 3)] = W2[L];
    }
    __syncthreads();
    int lane = t & 63;
    int w = t >> 6;
    float* hb = hbuf + w * 64;
    float bl = bias[lane];
    for (int it = 0; it < NITER; it++) {
        int wid = __builtin_amdgcn_readfirstlane((blockIdx.x * NITER + it) * 4 + w);
        if (wid >= N_NODES) return;
        int deg = min(__builtin_amdgcn_readfirstlane(cnt[wid]), CAP);
        float dvw = uni_f(dinv[wid]);
        float acc = (float)XW[(((unsigned)wid) << 6) | (unsigned)lane];
        acc += agg_edges(XW, ebuf, wid, deg, lane);
        float h = fmaxf(fmaf(dvw, acc, bl), 0.f);
        hb[lane] = h;
        float y = 0.f;
        #pragma unroll
        for (int k4 = 0; k4 < 16; k4++) {
            float4 hp = *(const float4*)(hb + k4 * 4);
            float4 wq = *(const float4*)(W2q + k4 * 256 + lane * 4);
            y = fmaf(hp.x, wq.x, y);
            y = fmaf(hp.y, wq.y, y);
            y = fmaf(hp.z, wq.z, y);
            y = fmaf(hp.w, wq.w, y);
        }
        Y2[(((unsigned)wid) << 6) | (unsigned)lane] = (h16)(y * dvw);
    }
}

__global__ __launch_bounds__(256) void agg_pool(const h16* __restrict__ XW,
                                                const int* __restrict__ cnt,
                                                const int* __restrict__ ebuf,
                                                const float* __restrict__ dinv,
                                                const float* __restrict__ bias,
                                                const float* __restrict__ Wout,
                                                const int* __restrict__ batch,
                                                float* __restrict__ outsum) {
    int lane = threadIdx.x & 63;
    int wid = __builtin_amdgcn_readfirstlane(blockIdx.x * 4 + (threadIdx.x >> 6));
    if (wid >= N_NODES) return;
    int deg = min(__builtin_amdgcn_readfirstlane(cnt[wid]), CAP);
    float dvw = uni_f(dinv[wid]);
    float acc = (float)XW[(((unsigned)wid) << 6) | (unsigned)lane];
    acc += agg_edges(XW, ebuf, wid, deg, lane);
    float h = fmaxf(fmaf(dvw, acc, bias[lane]), 0.f);
    float v = h * Wout[lane];
    #pragma unroll
    for (int off = 32; off > 0; off >>= 1) v += __shfl_down(v, off, 64);
    if (lane == 0) {
        int g = batch[wid];
        atomicAdd(&outsum[(wid & (NREP - 1)) * NUM_GRAPHS + g], v);
    }
}

__global__ __launch_bounds__(256) void finalize(const float* __restrict__ outsum,
                                                const int* __restrict__ batch,
                                                const float* __restrict__ bout,
                                                float* __restrict__ out) {
    int g = blockIdx.x * 256 + threadIdx.x;
    if (g >= NUM_GRAPHS) return;
    float s = 0.f;
    #pragma unroll
    for (int r = 0; r < NREP; r++) s += outsum[r * NUM_GRAPHS + g];
    int lo = 0, hi = N_NODES;
    while (lo < hi) { int mid = (lo + hi) >> 1; if (batch[mid] <  g) lo = mid + 1; else hi = mid; }
    int lo2 = lo, hi2 = N_NODES;
    while (lo2 < hi2) { int mid = (lo2 + hi2) >> 1; if (batch[mid] <= g) lo2 = mid + 1; else hi2 = mid; }
    float c = (float)max(lo2 - lo, 1);
    out[g] = s / c + bout[0];
}

// ---------------- launch ----------------

extern "C" void kernel_launch(void* const* d_in, const int* in_sizes, int n_in,
                              void* d_out, int out_size, void* d_ws, size_t ws_size,
                              hipStream_t stream) {
    const float* x     = (const float*)d_in[0];
    const int*   eidx  = (const int*)d_in[1];   // [2, E]
    const int*   batch = (const int*)d_in[2];
    const float* W1    = (const float*)d_in[3];
    const float* b1    = (const float*)d_in[4];
    const float* W2    = (const float*)d_in[5];
    const float* b2    = (const float*)d_in[6];
    const float* Wout  = (const float*)d_in[7];
    const float* bout  = (const float*)d_in[8];
    float* out = (float*)d_out;

    const int* src = eidx;
    const int* dst = eidx + N_EDGES;

    // workspace layout
    h16*   xw     = (h16*)d_ws;                             // (N+1)*64 fp16
    h16*   y2     = xw + (size_t)(N_NODES + 1) * 64;        // (N+1)*64 fp16
    int*   ebuf   = (int*)(y2 + (size_t)(N_NODES + 1) * 64);// 25.6 MB
    int*   cnt    = ebuf + (size_t)N_NODES * CAP;           // 400 KB
    float* outsum = (float*)(cnt + N_NODES);                // 32 KB (follows cnt)
    float* dinv   = outsum + NREP * NUM_GRAPHS;             // 400 KB

    void* args[] = {
        (void*)&src, (void*)&dst, (void*)&x,
        (void*)&W1, (void*)&b1, (void*)&W2, (void*)&b2,
        (void*)&Wout, (void*)&bout, (void*)&batch,
        (void*)&xw, (void*)&y2, (void*)&ebuf, (void*)&cnt,
        (void*)&outsum, (void*)&dinv, (void*)&out
    };

    // try cooperative mega-kernel at descending grid sizes; a failed
    // validation enqueues nothing, so fall through deterministically.
    hipError_t err = hipLaunchCooperativeKernel((void*)fused, dim3(1024), dim3(256),
                                                args, 0, stream);
    if (err != hipSuccess)
        err = hipLaunchCooperativeKernel((void*)fused, dim3(512), dim3(256),
                                         args, 0, stream);
    if (err != hipSuccess)
        err = hipLaunchCooperativeKernel((void*)fused, dim3(256), dim3(256),
                                         args, 0, stream);
    if (err == hipSuccess) return;

    // ---- fallback: R10 multi-kernel path ----
    hipMemsetAsync(cnt, 0, (size_t)(N_NODES + NREP * NUM_GRAPHS) * sizeof(int), stream);
    const int EB = (N_EDGES + 255) / 256;
    const int GB = (N_NODES + 127) / 128;
    const int AB = (N_NODES + 3) / 4;
    const int FB = (N_NODES + NITER * 4 - 1) / (NITER * 4);
    bucket_fill<<<EB * 8, 256, 0, stream>>>(src, dst, cnt, ebuf);
    gemm64h<<<GB, 256, 0, stream>>>(x, W1, cnt, dinv, xw, N_NODES);
    agg_gemm_relu<<<FB, 256, 0, stream>>>(xw, cnt, ebuf, dinv, b1, W2, y2);
    agg_pool<<<AB, 256, 0, stream>>>(y2, cnt, ebuf, dinv, b2, Wout, batch, outsum);
    finalize<<<(NUM_GRAPHS + 255) / 256, 256, 0, stream>>>(outsum, batch, bout, out);
}

// Round 14
// 249.887 us; speedup vs baseline: 3.2720x; 3.2720x over previous
//
#include <hip/hip_runtime.h>
#include <hip/hip_fp16.h>

#define N_NODES   100000
#define N_EDGES   1000000
#define HID       64
#define NUM_GRAPHS 1024
#define NREP      8    // outsum atomic replicas
#define CAP       64   // max in-degree bucket capacity (Poisson(10): max deg ~30)
#define NITER     16   // agg_gemm_relu: 64 nodes/block

typedef _Float16 h16;

static __device__ __forceinline__ int pack2(float a, float b) {
    union { h16 h[2]; int i; } u;
    u.h[0] = (h16)a; u.h[1] = (h16)b;
    return u.i;
}
static __device__ __forceinline__ float uni_f(float x) {
    return __int_as_float(__builtin_amdgcn_readfirstlane(__float_as_int(x)));
}

// ---------------- graph build: XCD-partitioned bucket fill ----------------
// Partition p owns dst granules where (d>>7)&7 == p; blockIdx&7 ~ XCD id.
// Keeps each partition's 3.2MB write set in one XCD L2 (R8: 60->~12MB writes).

__global__ __launch_bounds__(256) void bucket_fill(const int* __restrict__ src,
                                                   const int* __restrict__ dst,
                                                   int* __restrict__ cnt,
                                                   int* __restrict__ ebuf) {
    int part  = blockIdx.x & 7;
    int e     = (blockIdx.x >> 3) * 256 + threadIdx.x;
    if (e >= N_EDGES) return;
    int d = dst[e];
    if (((d >> 7) & 7) != part) return;
    int p = atomicAdd(&cnt[d], 1);
    if (p < CAP) ebuf[(size_t)d * CAP + p] = src[e];
}

// ---------------- XW' = (X @ W1) * dinv, fp16 out, fused node_prep --------
// 2 threads per row (32 channels each): acc=32 VGPR, adjacent lane-pairs
// share X cache lines. W broadcast from 16KB LDS.

__global__ __launch_bounds__(256) void gemm64h(const float* __restrict__ X,
                                               const float* __restrict__ W,
                                               const int* __restrict__ cnt,
                                               float* __restrict__ dinv,
                                               h16* __restrict__ Y, int nrows) {
    __shared__ float Wl[4096];
    int t = threadIdx.x;
    #pragma unroll
    for (int i = 0; i < 4; i++) {
        int idx = (t + i * 256) * 4;
        *(float4*)(Wl + idx) = *(const float4*)(W + idx);
    }
    __syncthreads();
    int row  = blockIdx.x * 128 + (t >> 1);
    if (row >= nrows) return;
    int half = t & 1;
    float df = (float)(min(cnt[row], CAP) + 1);   // +1 self loop
    float sc = rsqrtf(df);
    if (half == 0) dinv[row] = sc;
    const float4* xr = (const float4*)(X + (size_t)row * 64);
    float4 acc[8];
    #pragma unroll
    for (int j = 0; j < 8; j++) acc[j] = make_float4(0.f, 0.f, 0.f, 0.f);
    const float* wb = Wl + half * 32;
    #pragma unroll
    for (int k4 = 0; k4 < 16; k4++) {
        float4 xv = xr[k4];
        #pragma unroll
        for (int kk = 0; kk < 4; kk++) {
            float xk = (kk == 0) ? xv.x : (kk == 1) ? xv.y : (kk == 2) ? xv.z : xv.w;
            const float4* wr = (const float4*)(wb + (k4 * 4 + kk) * 64);
            #pragma unroll
            for (int j = 0; j < 8; j++) {
                float4 wv = wr[j];
                acc[j].x += xk * wv.x;
                acc[j].y += xk * wv.y;
                acc[j].z += xk * wv.z;
                acc[j].w += xk * wv.w;
            }
        }
    }
    int4* yr = (int4*)(Y + (size_t)row * 64 + half * 32);
    #pragma unroll
    for (int j = 0; j < 4; j++) {
        float4 a = acc[2 * j], b = acc[2 * j + 1];
        int4 o;
        o.x = pack2(a.x * sc, a.y * sc); o.y = pack2(a.z * sc, a.w * sc);
        o.z = pack2(b.x * sc, b.y * sc); o.w = pack2(b.z * sc, b.w * sc);
        yr[j] = o;
    }
}

// ---------------- aggregation: one wave per node, lane = channel ----------------
// es (full ebuf row) is loaded UNCONDITIONALLY and issued in parallel with
// cnt/dinv/self-row (no deg dependency: lanes >= deg hold garbage but are
// never selected by readlane — chunks only broadcast lanes j < deg).
// Critical path per node: max(ebuf, cnt) -> gathers, not cnt -> ebuf -> gathers.

template <int U>
static __device__ __forceinline__ float agg_chunk(const h16* __restrict__ XW,
                                                  int es, int j, int lane) {
    int ss[U]; float vv[U];
    #pragma unroll
    for (int u = 0; u < U; u++) ss[u] = __builtin_amdgcn_readlane(es, j + u);
    #pragma unroll
    for (int u = 0; u < U; u++)
        vv[u] = (float)XW[(((unsigned)ss[u]) << 6) | (unsigned)lane];
    float a = 0.f;
    #pragma unroll
    for (int u = 0; u < U; u++) a += vv[u];
    return a;
}

static __device__ __forceinline__ float agg_edges(const h16* __restrict__ XW,
                                                  int es, int deg, int lane) {
    float acc = 0.f;
    int j = 0;
    for (; j + 16 <= deg; j += 16) { acc += agg_chunk<16>(XW, es, j, lane); }
    if (deg & 8) { acc += agg_chunk<8>(XW, es, j, lane); j += 8; }
    if (deg & 4) { acc += agg_chunk<4>(XW, es, j, lane); j += 4; }
    if (deg & 2) { acc += agg_chunk<2>(XW, es, j, lane); j += 2; }
    if (deg & 1) { acc += agg_chunk<1>(XW, es, j, lane); }
    return acc;
}

// layer-1 agg + bias + ReLU + fused (h @ W2)*dinv -> Y2' (fp16).
// Block processes NITER*4 = 64 nodes; W2 staged ONCE per block.
// hbuf slices are wave-private -> no per-iteration __syncthreads needed.
__global__ __launch_bounds__(256) void agg_gemm_relu(const h16* __restrict__ XW,
                                                     const int* __restrict__ cnt,
                                                     const int* __restrict__ ebuf,
                                                     const float* __restrict__ dinv,
                                                     const float* __restrict__ bias,
                                                     const float* __restrict__ W2,
                                                     h16* __restrict__ Y2) {
    __shared__ float W2q[4096];   // W2q[(k>>2)*256 + c*4 + (k&3)]
    __shared__ float hbuf[256];   // 4 waves x 64, wave-private slices
    int t = threadIdx.x;
    #pragma unroll
    for (int i = 0; i < 16; i++) {
        int L = t + i * 256;            // L = k*64 + c
        int k = L >> 6, c = L & 63;
        W2q[(k >> 2) * 256 + c * 4 + (k & 3)] = W2[L];
    }
    __syncthreads();
    int lane = t & 63;
    int w = t >> 6;
    float* hb = hbuf + w * 64;
    float bl = bias[lane];
    for (int it = 0; it < NITER; it++) {
        int wid = __builtin_amdgcn_readfirstlane((blockIdx.x * NITER + it) * 4 + w);
        if (wid >= N_NODES) return;
        int es = ebuf[wid * CAP + lane];               // issue first (long pole)
        float self = (float)XW[(((unsigned)wid) << 6) | (unsigned)lane];
        int deg = min(__builtin_amdgcn_readfirstlane(cnt[wid]), CAP);
        float dvw = uni_f(dinv[wid]);
        float acc = self + agg_edges(XW, es, deg, lane);
        float h = fmaxf(fmaf(dvw, acc, bl), 0.f);
        hb[lane] = h;
        float y = 0.f;
        #pragma unroll
        for (int k4 = 0; k4 < 16; k4++) {
            float4 hp = *(const float4*)(hb + k4 * 4);              // broadcast
            float4 wq = *(const float4*)(W2q + k4 * 256 + lane * 4);
            y = fmaf(hp.x, wq.x, y);
            y = fmaf(hp.y, wq.y, y);
            y = fmaf(hp.z, wq.z, y);
            y = fmaf(hp.w, wq.w, y);
        }
        Y2[(((unsigned)wid) << 6) | (unsigned)lane] = (h16)(y * dvw);
    }
}

// layer-2 aggregation + ReLU + dot(Wout) + per-graph accumulation
__global__ __launch_bounds__(256) void agg_pool(const h16* __restrict__ XW,
                                                const int* __restrict__ cnt,
                                                const int* __restrict__ ebuf,
                                                const float* __restrict__ dinv,
                                                const float* __restrict__ bias,
                                                const float* __restrict__ Wout,
                                                const int* __restrict__ batch,
                                                float* __restrict__ outsum) {
    int lane = threadIdx.x & 63;
    int wid = __builtin_amdgcn_readfirstlane(blockIdx.x * 4 + (threadIdx.x >> 6));
    if (wid >= N_NODES) return;
    int es = ebuf[wid * CAP + lane];                   // issue first (long pole)
    float self = (float)XW[(((unsigned)wid) << 6) | (unsigned)lane];
    int deg = min(__builtin_amdgcn_readfirstlane(cnt[wid]), CAP);
    float dvw = uni_f(dinv[wid]);
    float acc = self + agg_edges(XW, es, deg, lane);
    float h = fmaxf(fmaf(dvw, acc, bias[lane]), 0.f);
    float v = h * Wout[lane];
    #pragma unroll
    for (int off = 32; off > 0; off >>= 1) v += __shfl_down(v, off, 64);
    if (lane == 0) {
        int g = batch[wid];
        atomicAdd(&outsum[(wid & (NREP - 1)) * NUM_GRAPHS + g], v);
    }
}

__global__ __launch_bounds__(256) void finalize(const float* __restrict__ outsum,
                                                const int* __restrict__ batch,
                                                const float* __restrict__ bout,
                                                float* __restrict__ out) {
    int g = blockIdx.x * 256 + threadIdx.x;
    if (g >= NUM_GRAPHS) return;
    float s = 0.f;
    #pragma unroll
    for (int r = 0; r < NREP; r++) s += outsum[r * NUM_GRAPHS + g];
    int lo = 0, hi = N_NODES;
    while (lo < hi) { int mid = (lo + hi) >> 1; if (batch[mid] <  g) lo = mid + 1; else hi = mid; }
    int lo2 = lo, hi2 = N_NODES;
    while (lo2 < hi2) { int mid = (lo2 + hi2) >> 1; if (batch[mid] <= g) lo2 = mid + 1; else hi2 = mid; }
    float c = (float)max(lo2 - lo, 1);
    out[g] = s / c + bout[0];
}

// ---------------- launch ----------------

extern "C" void kernel_launch(void* const* d_in, const int* in_sizes, int n_in,
                              void* d_out, int out_size, void* d_ws, size_t ws_size,
                              hipStream_t stream) {
    const float* x     = (const float*)d_in[0];
    const int*   eidx  = (const int*)d_in[1];   // [2, E]
    const int*   batch = (const int*)d_in[2];
    const float* W1    = (const float*)d_in[3];
    const float* b1    = (const float*)d_in[4];
    const float* W2    = (const float*)d_in[5];
    const float* b2    = (const float*)d_in[6];
    const float* Wout  = (const float*)d_in[7];
    const float* bout  = (const float*)d_in[8];
    float* out = (float*)d_out;

    const int* src = eidx;
    const int* dst = eidx + N_EDGES;

    // workspace layout
    h16*   xw     = (h16*)d_ws;                             // 12.8 MB
    h16*   y2     = xw + (size_t)N_NODES * 64;              // 12.8 MB
    int*   ebuf   = (int*)(y2 + (size_t)N_NODES * 64);      // 25.6 MB
    int*   cnt    = ebuf + (size_t)N_NODES * CAP;           // 400 KB
    float* outsum = (float*)(cnt + N_NODES);                // 32 KB (follows cnt)
    float* dinv   = outsum + NREP * NUM_GRAPHS;             // 400 KB

    // zero cnt + outsum (contiguous) — single memset
    hipMemsetAsync(cnt, 0, (size_t)(N_NODES + NREP * NUM_GRAPHS) * sizeof(int), stream);

    const int EB = (N_EDGES + 255) / 256;
    const int GB = (N_NODES + 127) / 128;                   // 2 threads per row
    const int AB = (N_NODES + 3) / 4;                       // agg_pool: 4 nodes/block
    const int FB = (N_NODES + NITER * 4 - 1) / (NITER * 4); // agg_gemm: 64 nodes/block

    bucket_fill<<<EB * 8, 256, 0, stream>>>(src, dst, cnt, ebuf);
    gemm64h<<<GB, 256, 0, stream>>>(x, W1, cnt, dinv, xw, N_NODES);
    agg_gemm_relu<<<FB, 256, 0, stream>>>(xw, cnt, ebuf, dinv, b1, W2, y2);
    agg_pool<<<AB, 256, 0, stream>>>(y2, cnt, ebuf, dinv, b2, Wout, batch, outsum);
    finalize<<<(NUM_GRAPHS + 255) / 256, 256, 0, stream>>>(outsum, batch, bout, out);
}